// Round 14
// baseline (26179.343 us; speedup 1.0000x reference)
//
#include <hip/hip_runtime.h>
#include <cmath>

// Model dims
#define TSTEPS 512
#define BB     128      // batch
#define HD     1024     // hidden
#define GD     4096     // 4*H
#define VD     128      // vocab
#define ED     128      // char emb
#define IE     32       // img emb
#define CD     160      // IE+ED

// DPP cross-lane move on the VALU pipe (no LDS). ctrl must be an immediate.
#define DPPMOV(v, ctrl) \
    __int_as_float(__builtin_amdgcn_update_dpp(0, __float_as_int(v), (ctrl), 0xF, 0xF, true))
#define DPP_XOR7  0x141   // row_half_mirror: lane ^= 7
#define DPP_XOR1  0x0B1   // quad_perm [1,0,3,2]
#define DPP_XOR2  0x04E   // quad_perm [2,3,0,1]
#define DPP_XOR8  0x128   // row_ror:8 == lane ^= 8 within 16-lane row

#define NTSTORE(p, v) __builtin_nontemporal_store((v), (p))

// ---------------- Fold kernels (run once per launch, trivial cost) ----------

__global__ void fold_wc_kernel(const float* __restrict__ W_ih,
                               const float* __restrict__ W_proj,
                               const float* __restrict__ b_proj,
                               const float* __restrict__ b_ih,
                               const float* __restrict__ b_hh,
                               float* __restrict__ Wc,
                               float* __restrict__ gb) {
    int idx = blockIdx.x * 256 + threadIdx.x;
    if (idx < GD * CD) {
        int g = idx / CD, c = idx - g * CD;
        const float* wr = W_ih + g * ED;
        float s = 0.f;
        #pragma unroll 8
        for (int e = 0; e < ED; ++e) s = fmaf(wr[e], W_proj[e * CD + c], s);
        Wc[idx] = s;
    }
    if (idx < GD) {
        const float* wr = W_ih + idx * ED;
        float s = b_ih[idx] + b_hh[idx];
        #pragma unroll 8
        for (int e = 0; e < ED; ++e) s = fmaf(wr[e], b_proj[e], s);
        gb[idx] = s;
    }
}

__global__ void fold_gimg_kernel(const float* __restrict__ emb_img,
                                 const int* __restrict__ input_img,
                                 const float* __restrict__ Wc,
                                 const float* __restrict__ gb,
                                 float* __restrict__ Gimgb) {
    int idx = blockIdx.x * 256 + threadIdx.x;   // BB*GD
    int b = idx >> 12, g = idx & (GD - 1);
    const float* e = emb_img + (size_t)input_img[b] * IE;
    const float* w = Wc + g * CD;
    float s = gb[g];
    #pragma unroll
    for (int k = 0; k < IE; ++k) s = fmaf(e[k], w[k], s);
    Gimgb[idx] = s;
}

__global__ void fold_gtok_kernel(const float* __restrict__ emb_char,
                                 const float* __restrict__ Wc,
                                 float* __restrict__ Gtok) {
    int idx = blockIdx.x * 256 + threadIdx.x;   // VD*GD
    int v = idx >> 12, g = idx & (GD - 1);
    const float* e = emb_char + v * ED;
    const float* w = Wc + g * CD + IE;
    float s = 0.f;
    #pragma unroll 8
    for (int k = 0; k < ED; ++k) s = fmaf(e[k], w[k], s);
    Gtok[idx] = s;
}

// zero hbuf + barrier flags (child + super), build tokseq[t][b]
__global__ void init_kernel(const int* __restrict__ x,
                            const int* __restrict__ label,
                            int* __restrict__ tokseq,
                            float* __restrict__ hbuf,
                            unsigned* __restrict__ barflags) {
    int idx = blockIdx.x * 256 + threadIdx.x;   // 1024 blocks * 256
    if (idx < 2 * BB * HD) hbuf[idx] = 0.f;
    if (idx < TSTEPS * BB) {
        int t = idx >> 7, b = idx & (BB - 1);
        tokseq[idx] = (t == 0) ? x[b * TSTEPS] : label[b * TSTEPS + t - 1];
    }
    if (idx < 4 * 128 * 16 + 4 * 8 * 16) barflags[idx] = 0;
}

// ---------------- Persistent-register LSTM + fused logits ------------------
// 512 blocks x 512 threads, regular launch, 2 blocks/CU. R12/R13-verified
// allocation: VGPR_Count=128, weight set resident (FETCH 1.2 GB). Compute
// structure byte-identical to R13. R14 changes ONLY sync traffic (R13
// post-mortem: ~35 us/step was the flat 128-flag poll storm — 128 lines x
// 64 lanes x every iteration, all in one XCD's L2):
//  - TWO-LEVEL flag tree per bgrp: children (128, 64B slots) -> 8
//    aggregators (jgrp<8, poll 16 children w/ 16 lanes) -> 8 superflags;
//    all blocks poll 8 superflags with 8 lanes. ~100x less poll traffic.
//  - hbuf back to CACHED stores (dirty/step = 512 KB chip-wide; R12's
//    flush-amp came from spill megabytes, gone since R12). Logits stay NT
//    (write-once stream; keeps L2/L3 clean, no reread by this kernel).
__global__ __launch_bounds__(512, 1) void lstm_fused(
    const float* __restrict__ W_hh,    // [4096][1024]
    const float* __restrict__ Gimgb,   // [128][4096]
    const float* __restrict__ Gtok,    // [128][4096]
    const float* __restrict__ Wfc,     // [128][1024]
    const float* __restrict__ bfc,     // [128]
    const int*   __restrict__ tokseq,  // [512][128]
    float*       __restrict__ hbuf,    // [2][128][1024]
    float*       __restrict__ logits,  // [128][512][128]
    unsigned*    __restrict__ barflags)// [4][128][16] + [4][8][16] super
{
    __shared__ float4 hlds4[16 * 256];  // 64 KiB

    const int tid  = threadIdx.x;
    const int bid  = blockIdx.x;
    const int bgrp = bid >> 7;          // 0..3
    const int jgrp = bid & 127;         // 0..127
    const int w    = tid >> 6;          // 0..7
    const int L    = tid & 63;
    const int col  = jgrp * 8 + w;      // 0..1023
    const int lrow = L & 31;
    const int row_own = bgrp * 32 + lrow;
    const int pcap = (L >> 3) & 3;      // pass that delivers row L&31
    const bool b0 = (L & 1), b1 = ((L >> 1) & 1), b2 = ((L >> 2) & 1);

    // logits: vocab = jgrp; 16 dots/stage (rows), 32 threads/dot over k
    const int dotid = tid >> 5;         // 0..15 local row
    const int kc    = tid & 31;
    const float bfcv = bfc[jgrp];

    const float4* __restrict__ Whh4 = reinterpret_cast<const float4*>(W_hh);
    const float4* __restrict__ Wfc4 = reinterpret_cast<const float4*>(Wfc);

    float4 wreg[4][4];
    #pragma unroll
    for (int g = 0; g < 4; ++g)
        #pragma unroll
        for (int i = 0; i < 4; ++i)
            wreg[g][i] = Whh4[(size_t)(g * HD + col) * 256 + i * 64 + L];

    // PIN: opaque to remat; in this shape the allocator keeps them resident.
    #pragma unroll
    for (int g = 0; g < 4; ++g)
        #pragma unroll
        for (int i = 0; i < 4; ++i)
            asm volatile("" : "+v"(wreg[g][i].x), "+v"(wreg[g][i].y),
                              "+v"(wreg[g][i].z), "+v"(wreg[g][i].w));

    unsigned* grpflags = barflags + bgrp * 128 * 16;
    unsigned* supflags = barflags + 4 * 128 * 16 + bgrp * 8 * 16;

    float ab0, ab1, ab2, ab3;
    {
        const int tok = tokseq[row_own];
        const float* gi = Gimgb + (size_t)row_own * GD + col;
        const float* gt = Gtok  + (size_t)tok     * GD + col;
        ab0 = gi[0]    + gt[0];
        ab1 = gi[1024] + gt[1024];
        ab2 = gi[2048] + gt[2048];
        ab3 = gi[3072] + gt[3072];
    }

    float c_reg = 0.f;
    int cur = 0;

    #pragma unroll 1
    for (int t = 0; t <= TSTEPS; ++t) {
        const bool last = (t == TSTEPS);
        float aval0 = 0.f, aval1 = 0.f, aval2 = 0.f, aval3 = 0.f;

        const float4* hsrc = reinterpret_cast<const float4*>(
            hbuf + (size_t)cur * (BB * HD));

        #pragma unroll 1
        for (int st = 0; st < 2; ++st) {
            // ---- stage 16 h rows into LDS (lane-dense layout) ----
            {
                const float4* src = hsrc + (size_t)(bgrp * 32 + st * 16) * 256;
                #pragma unroll
                for (int j = 0; j < 8; ++j)
                    hlds4[tid + j * 512] = src[tid + j * 512];
            }
            __syncthreads();

            // ---- logits for step t-1: rows st*16..+15, vocab jgrp ----
            if (t > 0) {
                float s = 0.f;
                #pragma unroll
                for (int m = 0; m < 8; ++m) {
                    float4 h4 = hlds4[dotid * 256 + m * 32 + kc];
                    float4 w4 = Wfc4[(size_t)jgrp * 256 + m * 32 + kc];
                    s = fmaf(h4.x, w4.x, fmaf(h4.y, w4.y,
                        fmaf(h4.z, w4.z, fmaf(h4.w, w4.w, s))));
                }
                s += __shfl_xor(s, 1);  s += __shfl_xor(s, 2);
                s += __shfl_xor(s, 4);  s += __shfl_xor(s, 8);
                s += __shfl_xor(s, 16);
                if (kc == 0)
                    NTSTORE(&logits[((size_t)(bgrp * 32 + st * 16 + dotid)
                            * TSTEPS + (t - 1)) * VD + jgrp], s + bfcv);
            }

            // ---- gate FMA + DPP butterfly: 2 passes of 8 rows ----
            if (!last) {
                #pragma unroll 1
                for (int p = 0; p < 2; ++p) {
                    float acc[4][8];
                    #pragma unroll
                    for (int g = 0; g < 4; ++g)
                        #pragma unroll
                        for (int r = 0; r < 8; ++r) acc[g][r] = 0.f;

                    #pragma unroll
                    for (int r = 0; r < 8; ++r) {
                        const int rl = p * 8 + r;
                        #pragma unroll
                        for (int i = 0; i < 4; ++i) {
                            float4 h4 = hlds4[rl * 256 + i * 64 + L];
                            #pragma unroll
                            for (int g = 0; g < 4; ++g)
                                acc[g][r] = fmaf(wreg[g][i].x, h4.x,
                                             fmaf(wreg[g][i].y, h4.y,
                                              fmaf(wreg[g][i].z, h4.z,
                                               fmaf(wreg[g][i].w, h4.w,
                                                    acc[g][r]))));
                        }
                    }

                    const bool own = (pcap == st * 2 + p);
                    #pragma unroll
                    for (int g = 0; g < 4; ++g) {
                        float m0 = b2 ? acc[g][4] : acc[g][0];
                        float s0 = b2 ? acc[g][0] : acc[g][4];
                        float m1 = b2 ? acc[g][5] : acc[g][1];
                        float s1 = b2 ? acc[g][1] : acc[g][5];
                        float m2 = b2 ? acc[g][6] : acc[g][2];
                        float s2 = b2 ? acc[g][2] : acc[g][6];
                        float m3 = b2 ? acc[g][7] : acc[g][3];
                        float s3 = b2 ? acc[g][3] : acc[g][7];
                        float n0 = m0 + DPPMOV(s0, DPP_XOR7);
                        float n1 = m1 + DPPMOV(s1, DPP_XOR7);
                        float n2 = m2 + DPPMOV(s2, DPP_XOR7);
                        float n3 = m3 + DPPMOV(s3, DPP_XOR7);
                        float p0k = b0 ? n1 : n0;
                        float p0s = b0 ? n0 : n1;
                        float p1k = b0 ? n3 : n2;
                        float p1s = b0 ? n2 : n3;
                        float q0 = p0k + DPPMOV(p0s, DPP_XOR1);
                        float q1 = p1k + DPPMOV(p1s, DPP_XOR1);
                        float rk = b1 ? q1 : q0;
                        float rs = b1 ? q0 : q1;
                        float u  = rk + DPPMOV(rs, DPP_XOR2);
                        u += DPPMOV(u, DPP_XOR8);
                        u += __int_as_float(__builtin_amdgcn_ds_swizzle(
                                 __float_as_int(u), 0x401F));   // xor16
                        u += __shfl_xor(u, 32);
                        if (g == 0)      aval0 = own ? u : aval0;
                        else if (g == 1) aval1 = own ? u : aval1;
                        else if (g == 2) aval2 = own ? u : aval2;
                        else             aval3 = own ? u : aval3;
                    }
                }
            }
            __syncthreads();
        }

        if (!last) {
            // torch gate order: i, f, g, o
            float a0 = aval0 + ab0, a1 = aval1 + ab1;
            float a2 = aval2 + ab2, a3 = aval3 + ab3;
            float ig = 1.f / (1.f + expf(-a0));
            float fg = 1.f / (1.f + expf(-a1));
            float gg = tanhf(a2);
            float og = 1.f / (1.f + expf(-a3));
            c_reg = fmaf(fg, c_reg, ig * gg);
            float hnew = og * tanhf(c_reg);
            if (L < 32)
                hbuf[(size_t)(cur ^ 1) * (BB * HD)
                     + (size_t)row_own * HD + col] = hnew;   // cached store

            // prefetch next step's biases (hides under barrier spin)
            if (t + 1 < TSTEPS) {
                const int tok = tokseq[(t + 1) * BB + row_own];
                const float* gi = Gimgb + (size_t)row_own * GD + col;
                const float* gt = Gtok  + (size_t)tok     * GD + col;
                ab0 = gi[0]    + gt[0];
                ab1 = gi[1024] + gt[1024];
                ab2 = gi[2048] + gt[2048];
                ab3 = gi[3072] + gt[3072];
            }

            // ---- two-level per-bgrp flag barrier ----
            __syncthreads();   // all waves' stores issued
            const unsigned target = (unsigned)(t + 1);
            if (tid == 0) {
                __builtin_amdgcn_fence(__ATOMIC_RELEASE, "agent");
                __hip_atomic_store(&grpflags[jgrp * 16], target,
                                   __ATOMIC_RELAXED, __HIP_MEMORY_SCOPE_AGENT);
            }
            if (jgrp < 8 && tid < 16) {
                // aggregator: poll my 16 children (16 lanes, 1 line each)
                for (;;) {
                    unsigned f = __hip_atomic_load(
                        &grpflags[(jgrp * 16 + tid) * 16],
                        __ATOMIC_RELAXED, __HIP_MEMORY_SCOPE_AGENT);
                    if (__all(f >= target)) break;
                    __builtin_amdgcn_s_sleep(1);
                }
                if (tid == 0) {
                    __builtin_amdgcn_fence(__ATOMIC_ACQ_REL, "agent");
                    __hip_atomic_store(&supflags[jgrp * 16], target,
                                       __ATOMIC_RELAXED, __HIP_MEMORY_SCOPE_AGENT);
                }
            }
            if (tid < 8) {
                for (;;) {
                    unsigned f = __hip_atomic_load(&supflags[tid * 16],
                        __ATOMIC_RELAXED, __HIP_MEMORY_SCOPE_AGENT);
                    if (__all(f >= target)) break;
                    __builtin_amdgcn_s_sleep(1);
                }
                __builtin_amdgcn_fence(__ATOMIC_ACQUIRE, "agent");
            }
            __syncthreads();
            cur ^= 1;
        }
    }
}

// ---------------- argmax (first-occurrence tie-break, preds as float) -------
__global__ void argmax_kernel(const float* __restrict__ logits,
                              float* __restrict__ preds) {
    int row = blockIdx.x * 4 + (threadIdx.x >> 6);   // 65536 rows
    int lane = threadIdx.x & 63;
    const float* r = logits + (size_t)row * VD;
    float v0 = r[lane * 2], v1 = r[lane * 2 + 1];
    float bv; int bi;
    if (v1 > v0) { bv = v1; bi = lane * 2 + 1; } else { bv = v0; bi = lane * 2; }
    #pragma unroll
    for (int d = 32; d >= 1; d >>= 1) {
        float ov = __shfl_down(bv, d);
        int   oi = __shfl_down(bi, d);
        if (ov > bv || (ov == bv && oi < bi)) { bv = ov; bi = oi; }
    }
    if (lane == 0) preds[row] = (float)bi;
}

// ---------------- launch ----------------------------------------------------
extern "C" void kernel_launch(void* const* d_in, const int* in_sizes, int n_in,
                              void* d_out, int out_size, void* d_ws, size_t ws_size,
                              hipStream_t stream) {
    const int*   input_img = (const int*)  d_in[0];
    const int*   x         = (const int*)  d_in[1];
    const int*   label     = (const int*)  d_in[2];
    const float* emb_img   = (const float*)d_in[3];
    const float* emb_char  = (const float*)d_in[4];
    const float* W_proj    = (const float*)d_in[5];
    const float* b_proj    = (const float*)d_in[6];
    const float* W_ih      = (const float*)d_in[7];
    const float* W_hh      = (const float*)d_in[8];
    const float* b_ih      = (const float*)d_in[9];
    const float* b_hh      = (const float*)d_in[10];
    const float* W_fc      = (const float*)d_in[11];
    const float* b_fc      = (const float*)d_in[12];

    float* ws      = (float*)d_ws;
    float* Wc      = ws;                          // 4096*160
    float* gb      = Wc + (size_t)GD * CD;        // 4096
    float* Gimgb   = gb + GD;                     // 128*4096
    float* Gtok    = Gimgb + (size_t)BB * GD;     // 128*4096
    float* hbuf    = Gtok + (size_t)VD * GD;      // 2*128*1024
    int*   tokseq  = (int*)(hbuf + 2 * (size_t)BB * HD);   // 512*128 ints
    unsigned* barflags = (unsigned*)(tokseq + TSTEPS * BB); // child+super flags

    float* logits = (float*)d_out;               // 128*512*128
    float* preds  = logits + (size_t)BB * TSTEPS * VD;

    fold_wc_kernel  <<<(GD * CD + 255) / 256, 256, 0, stream>>>(W_ih, W_proj, b_proj, b_ih, b_hh, Wc, gb);
    fold_gimg_kernel<<<(BB * GD) / 256, 256, 0, stream>>>(emb_img, input_img, Wc, gb, Gimgb);
    fold_gtok_kernel<<<(VD * GD) / 256, 256, 0, stream>>>(emb_char, Wc, Gtok);
    init_kernel     <<<1024, 256, 0, stream>>>(x, label, tokseq, hbuf, barflags);

    lstm_fused<<<512, 512, 0, stream>>>(W_hh, Gimgb, Gtok, W_fc, b_fc,
                                        tokseq, hbuf, logits, barflags);

    argmax_kernel<<<(BB * TSTEPS) / 4, 256, 0, stream>>>(logits, preds);
}

// Round 16
// 21001.204 us; speedup vs baseline: 1.2466x; 1.2466x over previous
//
#include <hip/hip_runtime.h>
#include <hip/hip_cooperative_groups.h>
#include <cmath>

// Model dims
#define TSTEPS 512
#define BB     128      // batch
#define HD     1024     // hidden
#define GD     4096     // 4*H
#define VD     128      // vocab
#define ED     128      // char emb
#define IE     32       // img emb
#define CD     160      // IE+ED

// DPP cross-lane move on the VALU pipe (no LDS). ctrl must be an immediate.
#define DPPMOV(v, ctrl) \
    __int_as_float(__builtin_amdgcn_update_dpp(0, __float_as_int(v), (ctrl), 0xF, 0xF, true))
#define DPP_XOR7  0x141   // row_half_mirror: lane ^= 7
#define DPP_XOR1  0x0B1   // quad_perm [1,0,3,2]
#define DPP_XOR2  0x04E   // quad_perm [2,3,0,1]
#define DPP_XOR8  0x128   // row_ror:8 == lane ^= 8 within 16-lane row

// ---------------- Fold kernels (run once per launch, trivial cost) ----------

__global__ void fold_wc_kernel(const float* __restrict__ W_ih,
                               const float* __restrict__ W_proj,
                               const float* __restrict__ b_proj,
                               const float* __restrict__ b_ih,
                               const float* __restrict__ b_hh,
                               float* __restrict__ Wc,
                               float* __restrict__ gb) {
    int idx = blockIdx.x * 256 + threadIdx.x;
    if (idx < GD * CD) {
        int g = idx / CD, c = idx - g * CD;
        const float* wr = W_ih + g * ED;
        float s = 0.f;
        #pragma unroll 8
        for (int e = 0; e < ED; ++e) s = fmaf(wr[e], W_proj[e * CD + c], s);
        Wc[idx] = s;
    }
    if (idx < GD) {
        const float* wr = W_ih + idx * ED;
        float s = b_ih[idx] + b_hh[idx];
        #pragma unroll 8
        for (int e = 0; e < ED; ++e) s = fmaf(wr[e], b_proj[e], s);
        gb[idx] = s;
    }
}

__global__ void fold_gimg_kernel(const float* __restrict__ emb_img,
                                 const int* __restrict__ input_img,
                                 const float* __restrict__ Wc,
                                 const float* __restrict__ gb,
                                 float* __restrict__ Gimgb) {
    int idx = blockIdx.x * 256 + threadIdx.x;   // BB*GD
    int b = idx >> 12, g = idx & (GD - 1);
    const float* e = emb_img + (size_t)input_img[b] * IE;
    const float* w = Wc + g * CD;
    float s = gb[g];
    #pragma unroll
    for (int k = 0; k < IE; ++k) s = fmaf(e[k], w[k], s);
    Gimgb[idx] = s;
}

__global__ void fold_gtok_kernel(const float* __restrict__ emb_char,
                                 const float* __restrict__ Wc,
                                 float* __restrict__ Gtok) {
    int idx = blockIdx.x * 256 + threadIdx.x;   // VD*GD
    int v = idx >> 12, g = idx & (GD - 1);
    const float* e = emb_char + v * ED;
    const float* w = Wc + g * CD + IE;
    float s = 0.f;
    #pragma unroll 8
    for (int k = 0; k < ED; ++k) s = fmaf(e[k], w[k], s);
    Gtok[idx] = s;
}

// zero hbuf + barrier counters, build transposed token stream tokseq[t][b]
__global__ void init_kernel(const int* __restrict__ x,
                            const int* __restrict__ label,
                            int* __restrict__ tokseq,
                            float* __restrict__ hbuf,
                            unsigned* __restrict__ barcnt) {
    int idx = blockIdx.x * 256 + threadIdx.x;   // 1024 blocks * 256
    if (idx < 2 * BB * HD) hbuf[idx] = 0.f;
    if (idx < TSTEPS * BB) {
        int t = idx >> 7, b = idx & (BB - 1);
        tokseq[idx] = (t == 0) ? x[b * TSTEPS] : label[b * TSTEPS + t - 1];
    }
    if (idx < 128) barcnt[idx] = 0;
}

// ---------------- Persistent-register cooperative LSTM + fused logits ------
// CHAMPION CONFIG (Round 7, 20,709 us, reproduced verbatim).
// 256 blocks x 1024 threads, COOPERATIVE launch (co-residency guaranteed —
// R15 post-mortem: 512-block regular-launch spin barriers were never truly
// co-resident [Occupancy 25% = 1 block/CU]; they ran on scheduler
// time-slicing and R15's variant livelocked).
// Block: bgrp=bid>>6 (32 batch rows), jgrp=bid&63 (16 cols). Wave w -> col
// jgrp*16+w. Lane L: 64-way interleaved k-split (f4 chunks i*64+L) ->
// lane-dense conflict-free ds_read_b128. Weights 64 VGPR, asm-pinned (the
// allocator still caps at 64 VGPR for 1024-thr blocks and spills, but the
// pin stops rematerialization; measured best overall).
// Butterfly: DPP value-halving (xor7/xor1/xor2) + sums (dpp xor8,
// ds_swizzle xor16, shfl xor32); capture pass (L>>3)&3 -> row L&31.
// Sync: 4 independent 64-block monotonic counter barriers (one per bgrp).
__global__ __launch_bounds__(1024, 4) void lstm_fused(
    const float* __restrict__ W_hh,    // [4096][1024]
    const float* __restrict__ Gimgb,   // [128][4096]
    const float* __restrict__ Gtok,    // [128][4096]
    const float* __restrict__ Wfc,     // [128][1024]
    const float* __restrict__ bfc,     // [128]
    const int*   __restrict__ tokseq,  // [512][128]
    float*       __restrict__ hbuf,    // [2][128][1024]
    float*       __restrict__ logits,  // [128][512][128]
    unsigned*    __restrict__ barcnt)  // [4][32]
{
    __shared__ float4 hlds4[16 * 256];  // 64 KiB

    const int tid  = threadIdx.x;
    const int bid  = blockIdx.x;
    const int bgrp = bid >> 6;          // 0..3
    const int jgrp = bid & 63;          // 0..63
    const int w    = tid >> 6;          // 0..15
    const int L    = tid & 63;
    const int col  = jgrp * 16 + w;     // 0..1023
    const int lrow = L & 31;
    const int row_own = bgrp * 32 + lrow;
    const int pcap = (L >> 3) & 3;
    const bool b0 = (L & 1), b1 = ((L >> 1) & 1), b2 = ((L >> 2) & 1);

    const int kc = L & 31;
    const int v  = jgrp * 2 + (L >> 5);
    const float bfcv = bfc[v];

    const float4* __restrict__ Whh4 = reinterpret_cast<const float4*>(W_hh);
    const float4* __restrict__ Wfc4 = reinterpret_cast<const float4*>(Wfc);

    float4 wreg[4][4];
    #pragma unroll
    for (int g = 0; g < 4; ++g)
        #pragma unroll
        for (int i = 0; i < 4; ++i)
            wreg[g][i] = Whh4[(size_t)(g * HD + col) * 256 + i * 64 + L];

    // PIN the weight set: asm "+v" makes each value opaque (cannot be
    // rematerialized from W_hh).
    #pragma unroll
    for (int g = 0; g < 4; ++g)
        #pragma unroll
        for (int i = 0; i < 4; ++i)
            asm volatile("" : "+v"(wreg[g][i].x), "+v"(wreg[g][i].y),
                              "+v"(wreg[g][i].z), "+v"(wreg[g][i].w));

    unsigned* cnt = barcnt + bgrp * 32;

    float ab0, ab1, ab2, ab3;
    {
        const int tok = tokseq[row_own];
        const float* gi = Gimgb + (size_t)row_own * GD + col;
        const float* gt = Gtok  + (size_t)tok     * GD + col;
        ab0 = gi[0]    + gt[0];
        ab1 = gi[1024] + gt[1024];
        ab2 = gi[2048] + gt[2048];
        ab3 = gi[3072] + gt[3072];
    }

    float c_reg = 0.f;
    int cur = 0;

    #pragma unroll 1
    for (int t = 0; t <= TSTEPS; ++t) {
        const bool last = (t == TSTEPS);
        float aval0 = 0.f, aval1 = 0.f, aval2 = 0.f, aval3 = 0.f;

        const float4* hsrc = reinterpret_cast<const float4*>(
            hbuf + (size_t)cur * (BB * HD));

        #pragma unroll 1
        for (int st = 0; st < 2; ++st) {
            {
                const float4* src = hsrc + (size_t)(bgrp * 32 + st * 16) * 256;
                #pragma unroll
                for (int j = 0; j < 4; ++j)
                    hlds4[tid + j * 1024] = src[tid + j * 1024];
            }
            __syncthreads();

            if (t > 0) {
                float s = 0.f;
                #pragma unroll
                for (int m = 0; m < 8; ++m) {
                    float4 h4 = hlds4[w * 256 + m * 32 + kc];
                    float4 w4 = Wfc4[(size_t)v * 256 + m * 32 + kc];
                    s = fmaf(h4.x, w4.x, fmaf(h4.y, w4.y,
                        fmaf(h4.z, w4.z, fmaf(h4.w, w4.w, s))));
                }
                s += __shfl_xor(s, 1);  s += __shfl_xor(s, 2);
                s += __shfl_xor(s, 4);  s += __shfl_xor(s, 8);
                s += __shfl_xor(s, 16);
                if (kc == 0)
                    logits[((size_t)(bgrp * 32 + st * 16 + w) * TSTEPS
                            + (t - 1)) * VD + v] = s + bfcv;
            }

            if (!last) {
                #pragma unroll 1
                for (int p = 0; p < 2; ++p) {
                    float acc[4][8];
                    #pragma unroll
                    for (int g = 0; g < 4; ++g)
                        #pragma unroll
                        for (int r = 0; r < 8; ++r) acc[g][r] = 0.f;

                    #pragma unroll
                    for (int r = 0; r < 8; ++r) {
                        const int rl = p * 8 + r;
                        #pragma unroll
                        for (int i = 0; i < 4; ++i) {
                            float4 h4 = hlds4[rl * 256 + i * 64 + L];
                            #pragma unroll
                            for (int g = 0; g < 4; ++g)
                                acc[g][r] = fmaf(wreg[g][i].x, h4.x,
                                             fmaf(wreg[g][i].y, h4.y,
                                              fmaf(wreg[g][i].z, h4.z,
                                               fmaf(wreg[g][i].w, h4.w,
                                                    acc[g][r]))));
                        }
                    }

                    const bool own = (pcap == st * 2 + p);
                    #pragma unroll
                    for (int g = 0; g < 4; ++g) {
                        float m0 = b2 ? acc[g][4] : acc[g][0];
                        float s0 = b2 ? acc[g][0] : acc[g][4];
                        float m1 = b2 ? acc[g][5] : acc[g][1];
                        float s1 = b2 ? acc[g][1] : acc[g][5];
                        float m2 = b2 ? acc[g][6] : acc[g][2];
                        float s2 = b2 ? acc[g][2] : acc[g][6];
                        float m3 = b2 ? acc[g][7] : acc[g][3];
                        float s3 = b2 ? acc[g][3] : acc[g][7];
                        float n0 = m0 + DPPMOV(s0, DPP_XOR7);
                        float n1 = m1 + DPPMOV(s1, DPP_XOR7);
                        float n2 = m2 + DPPMOV(s2, DPP_XOR7);
                        float n3 = m3 + DPPMOV(s3, DPP_XOR7);
                        float p0k = b0 ? n1 : n0;
                        float p0s = b0 ? n0 : n1;
                        float p1k = b0 ? n3 : n2;
                        float p1s = b0 ? n2 : n3;
                        float q0 = p0k + DPPMOV(p0s, DPP_XOR1);
                        float q1 = p1k + DPPMOV(p1s, DPP_XOR1);
                        float rk = b1 ? q1 : q0;
                        float rs = b1 ? q0 : q1;
                        float u  = rk + DPPMOV(rs, DPP_XOR2);
                        u += DPPMOV(u, DPP_XOR8);
                        u += __int_as_float(__builtin_amdgcn_ds_swizzle(
                                 __float_as_int(u), 0x401F));   // xor16
                        u += __shfl_xor(u, 32);
                        if (g == 0)      aval0 = own ? u : aval0;
                        else if (g == 1) aval1 = own ? u : aval1;
                        else if (g == 2) aval2 = own ? u : aval2;
                        else             aval3 = own ? u : aval3;
                    }
                }
            }
            __syncthreads();
        }

        if (!last) {
            float a0 = aval0 + ab0, a1 = aval1 + ab1;
            float a2 = aval2 + ab2, a3 = aval3 + ab3;
            float ig = 1.f / (1.f + expf(-a0));
            float fg = 1.f / (1.f + expf(-a1));
            float gg = tanhf(a2);
            float og = 1.f / (1.f + expf(-a3));
            c_reg = fmaf(fg, c_reg, ig * gg);
            float hnew = og * tanhf(c_reg);
            if (L < 32)
                hbuf[(size_t)(cur ^ 1) * (BB * HD)
                     + (size_t)row_own * HD + col] = hnew;

            if (t + 1 < TSTEPS) {
                const int tok = tokseq[(t + 1) * BB + row_own];
                const float* gi = Gimgb + (size_t)row_own * GD + col;
                const float* gt = Gtok  + (size_t)tok     * GD + col;
                ab0 = gi[0]    + gt[0];
                ab1 = gi[1024] + gt[1024];
                ab2 = gi[2048] + gt[2048];
                ab3 = gi[3072] + gt[3072];
            }

            __syncthreads();
            if (tid == 0) {
                __hip_atomic_fetch_add(cnt, 1u, __ATOMIC_RELEASE,
                                       __HIP_MEMORY_SCOPE_AGENT);
                const unsigned target = 64u * (unsigned)(t + 1);
                while (__hip_atomic_load(cnt, __ATOMIC_ACQUIRE,
                                         __HIP_MEMORY_SCOPE_AGENT) < target)
                    __builtin_amdgcn_s_sleep(1);
            }
            __syncthreads();
            cur ^= 1;
        }
    }
}

// ---------------- argmax (first-occurrence tie-break, preds as float) -------
__global__ void argmax_kernel(const float* __restrict__ logits,
                              float* __restrict__ preds) {
    int row = blockIdx.x * 4 + (threadIdx.x >> 6);   // 65536 rows
    int lane = threadIdx.x & 63;
    const float* r = logits + (size_t)row * VD;
    float v0 = r[lane * 2], v1 = r[lane * 2 + 1];
    float bv; int bi;
    if (v1 > v0) { bv = v1; bi = lane * 2 + 1; } else { bv = v0; bi = lane * 2; }
    #pragma unroll
    for (int d = 32; d >= 1; d >>= 1) {
        float ov = __shfl_down(bv, d);
        int   oi = __shfl_down(bi, d);
        if (ov > bv || (ov == bv && oi < bi)) { bv = ov; bi = oi; }
    }
    if (lane == 0) preds[row] = (float)bi;
}

// ---------------- launch ----------------------------------------------------
extern "C" void kernel_launch(void* const* d_in, const int* in_sizes, int n_in,
                              void* d_out, int out_size, void* d_ws, size_t ws_size,
                              hipStream_t stream) {
    const int*   input_img = (const int*)  d_in[0];
    const int*   x         = (const int*)  d_in[1];
    const int*   label     = (const int*)  d_in[2];
    const float* emb_img   = (const float*)d_in[3];
    const float* emb_char  = (const float*)d_in[4];
    const float* W_proj    = (const float*)d_in[5];
    const float* b_proj    = (const float*)d_in[6];
    const float* W_ih      = (const float*)d_in[7];
    const float* W_hh      = (const float*)d_in[8];
    const float* b_ih      = (const float*)d_in[9];
    const float* b_hh      = (const float*)d_in[10];
    const float* W_fc      = (const float*)d_in[11];
    const float* b_fc      = (const float*)d_in[12];

    float* ws      = (float*)d_ws;
    float* Wc      = ws;                          // 4096*160
    float* gb      = Wc + (size_t)GD * CD;        // 4096
    float* Gimgb   = gb + GD;                     // 128*4096
    float* Gtok    = Gimgb + (size_t)BB * GD;     // 128*4096
    float* hbuf    = Gtok + (size_t)VD * GD;      // 2*128*1024
    int*   tokseq  = (int*)(hbuf + 2 * (size_t)BB * HD);   // 512*128 ints
    unsigned* barcnt = (unsigned*)(tokseq + TSTEPS * BB);  // 128 uints

    float* logits = (float*)d_out;               // 128*512*128
    float* preds  = logits + (size_t)BB * TSTEPS * VD;

    fold_wc_kernel  <<<(GD * CD + 255) / 256, 256, 0, stream>>>(W_ih, W_proj, b_proj, b_ih, b_hh, Wc, gb);
    fold_gimg_kernel<<<(BB * GD) / 256, 256, 0, stream>>>(emb_img, input_img, Wc, gb, Gimgb);
    fold_gtok_kernel<<<(VD * GD) / 256, 256, 0, stream>>>(emb_char, Wc, Gtok);
    init_kernel     <<<1024, 256, 0, stream>>>(x, label, tokseq, hbuf, barcnt);

    void* kargs[] = { (void*)&W_hh, (void*)&Gimgb, (void*)&Gtok, (void*)&W_fc,
                      (void*)&b_fc, (void*)&tokseq, (void*)&hbuf, (void*)&logits,
                      (void*)&barcnt };
    hipLaunchCooperativeKernel((void*)lstm_fused, dim3(256), dim3(1024), kargs, 0, stream);

    argmax_kernel<<<(BB * TSTEPS) / 4, 256, 0, stream>>>(logits, preds);
}